// Round 1
// baseline (9.737 us; speedup 1.0000x reference)
//
#include <hip/hip_runtime.h>

// MEE loss: out = gauss_norm/N^2 * sum_{i,j} exp(-(e_i - e_j)/(2 sigma^2))
// with e = |y_true - y_pred|. Exponent is LINEAR in e_i, e_j, so it
// factorizes: sum_{i,j} = (sum_i exp(-e_i/c)) * (sum_j exp(+e_j/c)),
// c = 2 sigma^2. O(N^2) -> O(N). N = 8192 -> single-block reduction.

#define PI_LITERAL 3.14159f  // module uses this literal, not pi

__global__ __launch_bounds__(256) void mee_loss_kernel(
    const float* __restrict__ y_pred,
    const float* __restrict__ y_true,
    const float* __restrict__ kernel_width,
    float* __restrict__ out,
    int n) {
    const int tid = threadIdx.x;
    const float sigma = kernel_width[0];
    const float inv_c = 1.0f / (2.0f * sigma * sigma);  // 1/(2 sigma^2)

    double sp = 0.0;  // sum of exp(+e/c)
    double sm = 0.0;  // sum of exp(-e/c)

    // float4 vectorized main loop (n = 8192 is divisible by 4)
    const float4* yp4 = reinterpret_cast<const float4*>(y_pred);
    const float4* yt4 = reinterpret_cast<const float4*>(y_true);
    const int n4 = n >> 2;
    for (int i = tid; i < n4; i += 256) {
        const float4 a = yp4[i];
        const float4 b = yt4[i];
        const float e0 = fabsf(b.x - a.x);
        const float e1 = fabsf(b.y - a.y);
        const float e2 = fabsf(b.z - a.z);
        const float e3 = fabsf(b.w - a.w);
        sp += (double)expf(e0 * inv_c) + (double)expf(e1 * inv_c)
            + (double)expf(e2 * inv_c) + (double)expf(e3 * inv_c);
        sm += (double)expf(-e0 * inv_c) + (double)expf(-e1 * inv_c)
            + (double)expf(-e2 * inv_c) + (double)expf(-e3 * inv_c);
    }
    // scalar tail (none for n % 4 == 0, kept for generality)
    for (int i = (n4 << 2) + tid; i < n; i += 256) {
        const float e = fabsf(y_true[i] - y_pred[i]);
        sp += (double)expf(e * inv_c);
        sm += (double)expf(-e * inv_c);
    }

    // wave64 butterfly reduction
    for (int off = 32; off > 0; off >>= 1) {
        sp += __shfl_down(sp, off);
        sm += __shfl_down(sm, off);
    }

    __shared__ double lds_sp[4];
    __shared__ double lds_sm[4];
    const int wave = tid >> 6;
    const int lane = tid & 63;
    if (lane == 0) {
        lds_sp[wave] = sp;
        lds_sm[wave] = sm;
    }
    __syncthreads();

    if (tid == 0) {
        const double SP = lds_sp[0] + lds_sp[1] + lds_sp[2] + lds_sp[3];
        const double SM = lds_sm[0] + lds_sm[1] + lds_sm[2] + lds_sm[3];
        const float gauss_norm = 1.0f / (sqrtf(2.0f * PI_LITERAL) * sigma);
        const double total =
            (double)gauss_norm * SP * SM / ((double)n * (double)n);
        out[0] = (float)total;
    }
}

extern "C" void kernel_launch(void* const* d_in, const int* in_sizes, int n_in,
                              void* d_out, int out_size, void* d_ws, size_t ws_size,
                              hipStream_t stream) {
    const float* y_pred = (const float*)d_in[0];
    const float* y_true = (const float*)d_in[1];
    const float* kernel_width = (const float*)d_in[2];
    float* out = (float*)d_out;
    const int n = in_sizes[0];

    mee_loss_kernel<<<1, 256, 0, stream>>>(y_pred, y_true, kernel_width, out, n);
}

// Round 2
// 9.702 us; speedup vs baseline: 1.0036x; 1.0036x over previous
//
#include <hip/hip_runtime.h>

// MEE loss: out = gauss_norm/N^2 * sum_{i,j} exp(-(e_i - e_j)/(2 sigma^2))
// with e = |y_true - y_pred|. Exponent is LINEAR in e_i, e_j, so it
// factorizes: sum_{i,j} = (sum_i exp(-e_i/c)) * (sum_j exp(+e_j/c)),
// c = 2 sigma^2. O(N^2) -> O(N). N = 8192 -> single-block reduction.
//
// 1024 threads (16 waves on 1 CU) for latency hiding; exp(-x) = rcp(exp(x))
// halves transcendental count. f64 accumulation for summation-order safety.

#define PI_LITERAL 3.14159f  // module uses this literal, not pi

__global__ __launch_bounds__(1024) void mee_loss_kernel(
    const float* __restrict__ y_pred,
    const float* __restrict__ y_true,
    const float* __restrict__ kernel_width,
    float* __restrict__ out,
    int n) {
    const int tid = threadIdx.x;
    const int nthreads = blockDim.x;
    const float sigma = kernel_width[0];
    const float inv_c = 1.0f / (2.0f * sigma * sigma);  // 1/(2 sigma^2)

    double sp = 0.0;  // sum of exp(+e/c)
    double sm = 0.0;  // sum of exp(-e/c)

    // float4 vectorized main loop (n = 8192 divisible by 4)
    const float4* yp4 = reinterpret_cast<const float4*>(y_pred);
    const float4* yt4 = reinterpret_cast<const float4*>(y_true);
    const int n4 = n >> 2;
    for (int i = tid; i < n4; i += nthreads) {
        const float4 a = yp4[i];
        const float4 b = yt4[i];
        const float e0 = fabsf(b.x - a.x);
        const float e1 = fabsf(b.y - a.y);
        const float e2 = fabsf(b.z - a.z);
        const float e3 = fabsf(b.w - a.w);
        const float t0 = expf(e0 * inv_c);
        const float t1 = expf(e1 * inv_c);
        const float t2 = expf(e2 * inv_c);
        const float t3 = expf(e3 * inv_c);
        sp += (double)t0 + (double)t1 + (double)t2 + (double)t3;
        sm += (double)(1.0f / t0) + (double)(1.0f / t1)
            + (double)(1.0f / t2) + (double)(1.0f / t3);
    }
    // scalar tail (none for n % 4 == 0, kept for generality)
    for (int i = (n4 << 2) + tid; i < n; i += nthreads) {
        const float e = fabsf(y_true[i] - y_pred[i]);
        const float t = expf(e * inv_c);
        sp += (double)t;
        sm += (double)(1.0f / t);
    }

    // wave64 butterfly reduction
    for (int off = 32; off > 0; off >>= 1) {
        sp += __shfl_down(sp, off);
        sm += __shfl_down(sm, off);
    }

    __shared__ double lds_sp[16];
    __shared__ double lds_sm[16];
    const int wave = tid >> 6;
    const int lane = tid & 63;
    const int nwaves = nthreads >> 6;
    if (lane == 0) {
        lds_sp[wave] = sp;
        lds_sm[wave] = sm;
    }
    __syncthreads();

    if (tid == 0) {
        double SP = 0.0, SM = 0.0;
        for (int w = 0; w < nwaves; ++w) {
            SP += lds_sp[w];
            SM += lds_sm[w];
        }
        const float gauss_norm = 1.0f / (sqrtf(2.0f * PI_LITERAL) * sigma);
        const double total =
            (double)gauss_norm * SP * SM / ((double)n * (double)n);
        out[0] = (float)total;
    }
}

extern "C" void kernel_launch(void* const* d_in, const int* in_sizes, int n_in,
                              void* d_out, int out_size, void* d_ws, size_t ws_size,
                              hipStream_t stream) {
    const float* y_pred = (const float*)d_in[0];
    const float* y_true = (const float*)d_in[1];
    const float* kernel_width = (const float*)d_in[2];
    float* out = (float*)d_out;
    const int n = in_sizes[0];

    mee_loss_kernel<<<1, 1024, 0, stream>>>(y_pred, y_true, kernel_width, out, n);
}